// Round 12
// baseline (401.882 us; speedup 1.0000x reference)
//
#include <hip/hip_runtime.h>
#include <hip/hip_bf16.h>
#include <hip/hip_cooperative_groups.h>

namespace cg = cooperative_groups;

constexpr int N  = 50000;
constexpr int E  = 800000;
constexpr int F0 = 128;
constexpr int H1 = 32;
constexpr int F1 = 256;
constexpr int F2 = 64;
constexpr int NB = (N + 255) / 256;        // 196 scan blocks
constexpr int NPAD = 782 * 64;             // 50048
constexpr int W1SZ = F0 * F1;              // 32768
constexpr int W2SZ = F1 * F2;              // 16384
constexpr int VA1SZ = 64 * F0;             // 8192
constexpr int VA2SZ = 16 * F1;             // 4096
constexpr int PREPB = (W1SZ + W2SZ + VA1SZ + VA2SZ) / 256;  // 240
constexpr int INITB = PREPB + NB;          // 436
constexpr int GB1 = NPAD / 64;             // 782 gemm1 blocks
constexpr int CB  = (E + 255) / 256;       // 3125 edge-grid blocks
constexpr int CSRB = 1024;                 // cooperative grid (<=2048 co-resident)
constexpr float NEG_SLOPE = 0.2f;

typedef unsigned short u16;
typedef unsigned int   u32;
typedef __attribute__((ext_vector_type(8))) short bf16x8;
typedef __attribute__((ext_vector_type(4))) float f32x4;
typedef __attribute__((ext_vector_type(2))) float f32x2;

__device__ __forceinline__ float leaky(float e) {
    return fmaxf(e, 0.f) + NEG_SLOPE * fminf(e, 0.f);
}
__device__ __forceinline__ float bf2f(u16 u) {
    u32 v = ((u32)u) << 16;
    return __builtin_bit_cast(float, v);
}
__device__ __forceinline__ u16 f2bf(float f) {
    u32 u = __builtin_bit_cast(u32, f);
    u += 0x7fffu + ((u >> 16) & 1u);
    return (u16)(u >> 16);
}
__device__ __forceinline__ u32 pack2(float a, float b) {
    return (u32)f2bf(a) | ((u32)f2bf(b) << 16);
}
__device__ __forceinline__ f32x2 up2v(u32 v) {
    f32x2 r;
    r.x = __builtin_bit_cast(float, v << 16);
    r.y = __builtin_bit_cast(float, v & 0xffff0000u);
    return r;
}

// in-wave edge_index dtype check: int64 data -> first 64 u64 all < N
__device__ __forceinline__ int is64_check(const void* ei) {
    const unsigned long long* p = (const unsigned long long*)ei;
    unsigned long long v = p[threadIdx.x & 63];
    return __all(v < (unsigned long long)N) ? 1 : 0;
}
__device__ __forceinline__ int load_idx(const void* ei, long long i, int is64) {
    return is64 ? (int)((const long long*)ei)[i] : ((const int*)ei)[i];
}

// ---------------------------------------------------------------------------
// 0. init: prep weights (fp32->bf16, [n][k] transposed, pre-swizzled) +
//    folded attention cols, AND zero deg. One dispatch.
__global__ __launch_bounds__(256) void k_init(
        const float* __restrict__ W1, const float* __restrict__ W2,
        const float* __restrict__ as1, const float* __restrict__ ad1,
        const float* __restrict__ a2s, const float* __restrict__ a2d,
        u16* __restrict__ w1t, u16* __restrict__ w2t,
        u16* __restrict__ va1t, u16* __restrict__ va2t, int* __restrict__ deg) {
    int b = blockIdx.x;
    if (b >= PREPB) {
        int i = (b - PREPB) * 256 + threadIdx.x;
        if (i < N) deg[i] = 0;
        return;
    }
    int i = b * 256 + threadIdx.x;
    if (i < W1SZ) {
        int n = i >> 7, k = i & 127;
        w1t[(n << 7) + (k ^ ((n & 7) << 3))] = f2bf(W1[k * F1 + n]);
    } else if (i < W1SZ + W2SZ) {
        int j = i - W1SZ;
        int n = j >> 8, k = j & 255;
        w2t[(n << 8) + (k ^ ((n & 7) << 3))] = f2bf(W2[k * F2 + n]);
    } else if (i < W1SZ + W2SZ + VA1SZ) {
        int j = i - W1SZ - W2SZ;
        int c = j >> 7, k = j & 127;          // c: 0-31 src, 32-63 dst
        const float* a = (c < 32) ? as1 : ad1;
        int h = c & 31;
        float s = 0.f;
#pragma unroll
        for (int cc = 0; cc < 8; cc++) s += W1[k * F1 + h * 8 + cc] * a[h * 8 + cc];
        va1t[(c << 7) + (k ^ ((c & 7) << 3))] = f2bf(s);
    } else if (i < W1SZ + W2SZ + VA1SZ + VA2SZ) {
        int j = i - W1SZ - W2SZ - VA1SZ;
        int jj = j >> 8, k = j & 255;
        float s = 0.f;
        if (jj < 2) {
            const float* a = jj ? a2d : a2s;
            for (int c = 0; c < 64; c++) s += W2[k * F2 + c] * a[c];
        }
        va2t[(jj << 8) + (k ^ ((jj & 7) << 3))] = f2bf(s);
    }
}

// ---------------------------------------------------------------------------
// 1. Fused GEMM1 (MFMA, blocks < GB1) + edge COUNT (blocks >= GB1).
__global__ __launch_bounds__(256) void k_gemm1count(
        const float* __restrict__ x, const u16* __restrict__ w1t,
        const u16* __restrict__ va1t, const float* __restrict__ b1,
        u16* __restrict__ h1b, u16* __restrict__ asrc1b, u16* __restrict__ adst1b,
        const void* __restrict__ ei, int* __restrict__ deg) {
    if (blockIdx.x >= GB1) {
        int is64 = is64_check(ei);
        int e = (blockIdx.x - GB1) * 256 + threadIdx.x;
        if (e < E) {
            int dst = load_idx(ei, (long long)E + e, is64);
            atomicAdd(&deg[dst], 1);
        }
        return;
    }
    __shared__ u16 As[64 * 128];   // 16KB, swizzled rows
    int r0 = blockIdx.x * 64;
    int t = threadIdx.x, w = t >> 6, l = t & 63;
    {   // stage: thread t -> row t>>2, 32 cols at (t&3)*32; fp32->bf16 inline
        int r = t >> 2, k0 = (t & 3) * 32, rr = r0 + r;
        int swz = (r & 7) << 3;
        float4 f[8];
        if (rr < N) {
            const float4* px = (const float4*)(x + (size_t)rr * F0 + k0);
#pragma unroll
            for (int j = 0; j < 8; j++) f[j] = px[j];
        } else {
#pragma unroll
            for (int j = 0; j < 8; j++) f[j] = make_float4(0.f, 0.f, 0.f, 0.f);
        }
#pragma unroll
        for (int g = 0; g < 4; g++) {
            uint4 st;
            st.x = pack2(f[2 * g].x, f[2 * g].y);
            st.y = pack2(f[2 * g].z, f[2 * g].w);
            st.z = pack2(f[2 * g + 1].x, f[2 * g + 1].y);
            st.w = pack2(f[2 * g + 1].z, f[2 * g + 1].w);
            *(uint4*)(As + r * 128 + ((k0 + 8 * g) ^ swz)) = st;
        }
    }
    bf16x8 bfrag[4][4];
    float b1v[4];
#pragma unroll
    for (int n = 0; n < 4; n++) {
        int col = w * 64 + n * 16 + (l & 15);
        b1v[n] = b1[col];
        const u16* wrow = w1t + col * 128;
        int swz = (col & 7) << 3;
#pragma unroll
        for (int ks = 0; ks < 4; ks++)
            bfrag[n][ks] = *(const bf16x8*)(wrow + ((ks * 32 + (l >> 4) * 8) ^ swz));
    }
    __syncthreads();
    f32x4 z = {0.f, 0.f, 0.f, 0.f};
    f32x4 acc[4][4], acc5[4];
#pragma unroll
    for (int m = 0; m < 4; m++) {
        acc5[m] = z;
#pragma unroll
        for (int n = 0; n < 4; n++) acc[m][n] = z;
    }
    int c5 = w * 16 + (l & 15);               // alpha col 0..63
    const u16* varow = va1t + c5 * 128;
    int swz5 = (c5 & 7) << 3;
#pragma unroll
    for (int ks = 0; ks < 4; ks++) {
        bf16x8 b5 = *(const bf16x8*)(varow + ((ks * 32 + (l >> 4) * 8) ^ swz5));
#pragma unroll
        for (int m = 0; m < 4; m++) {
            int row = m * 16 + (l & 15);
            bf16x8 a = *(const bf16x8*)(As + row * 128 +
                                        ((ks * 32 + (l >> 4) * 8) ^ ((row & 7) << 3)));
#pragma unroll
            for (int n = 0; n < 4; n++)
                acc[m][n] = __builtin_amdgcn_mfma_f32_16x16x32_bf16(a, bfrag[n][ks], acc[m][n], 0, 0, 0);
            acc5[m] = __builtin_amdgcn_mfma_f32_16x16x32_bf16(a, b5, acc5[m], 0, 0, 0);
        }
    }
#pragma unroll
    for (int m = 0; m < 4; m++) {
        int rbase = r0 + m * 16 + (l >> 4) * 4;
#pragma unroll
        for (int n = 0; n < 4; n++) {
            int col = w * 64 + n * 16 + (l & 15);
#pragma unroll
            for (int r = 0; r < 4; r++) {
                int rr = rbase + r;
                if (rr < N)
                    h1b[(size_t)rr * 256 + (col ^ ((rr & 7) << 3))] = f2bf(acc[m][n][r] + b1v[n]);
            }
        }
#pragma unroll
        for (int r = 0; r < 4; r++) {
            int rr = rbase + r;
            if (rr < N) {
                u16 v = f2bf(acc5[m][r]);
                if (c5 < 32) asrc1b[(size_t)rr * H1 + c5] = v;
                else         adst1b[(size_t)rr * H1 + (c5 - 32)] = v;
            }
        }
    }
}

// ---------------------------------------------------------------------------
// 2. COOPERATIVE CSR chain: bsum -> grid.sync -> scan(rs,rs2) -> grid.sync
//    -> scatter. Replaces 3 dispatches + 2 launch gaps.
__global__ __launch_bounds__(256) void k_csr(
        const void* __restrict__ ei, const int* __restrict__ deg,
        int* __restrict__ bsum, int* __restrict__ rs,
        int* __restrict__ rs2, int* __restrict__ csr) {
    cg::grid_group grid = cg::this_grid();
    int t = threadIdx.x, lane = t & 63, wy = t >> 6;
    __shared__ int sw[4];
    // phase A: per-chunk block sums of deg
    for (int b = blockIdx.x; b < NB; b += gridDim.x) {
        int i = b * 256 + t;
        int v = (i < N) ? deg[i] : 0;
#pragma unroll
        for (int o = 1; o < 64; o <<= 1) v += __shfl_xor(v, o, 64);
        if (lane == 0) sw[wy] = v;
        __syncthreads();
        if (t == 0) bsum[b] = sw[0] + sw[1] + sw[2] + sw[3];
        __syncthreads();
    }
    grid.sync();
    // phase B: every block scans the 196 block sums, then its own chunks
    {
        __shared__ int sb[NB];
        __shared__ int wtot[4], wtot2[4];
        int v = (t < NB) ? bsum[t] : 0;
        int inc = v;
#pragma unroll
        for (int o = 1; o < 64; o <<= 1) { int u = __shfl_up(inc, o, 64); if (lane >= o) inc += u; }
        if (lane == 63) wtot[wy] = inc;
        __syncthreads();
        int offs = 0;
        for (int k = 0; k < wy; k++) offs += wtot[k];
        if (t < NB) sb[t] = offs + inc - v;
        if (blockIdx.x == 0 && t == NB - 1) rs[N] = offs + inc;
        __syncthreads();
        for (int b = blockIdx.x; b < NB; b += gridDim.x) {
            int i = b * 256 + t;
            int dv = (i < N) ? deg[i] : 0;
            int dinc = dv;
#pragma unroll
            for (int o = 1; o < 64; o <<= 1) { int u = __shfl_up(dinc, o, 64); if (lane >= o) dinc += u; }
            if (lane == 63) wtot2[wy] = dinc;
            __syncthreads();
            int o2 = sb[b];
            for (int k = 0; k < wy; k++) o2 += wtot2[k];
            if (i < N) {
                int e0 = o2 + dinc - dv;
                rs[i] = e0;
                rs2[i] = e0;
            }
            __syncthreads();
        }
    }
    grid.sync();
    // phase C: scatter (grid-stride)
    int is64 = is64_check(ei);
    for (int e = blockIdx.x * 256 + t; e < E; e += gridDim.x * 256) {
        int src = load_idx(ei, e, is64);
        int dst = load_idx(ei, (long long)E + e, is64);
        int pos = atomicAdd(&rs2[dst], 1);
        csr[pos] = src;
    }
}

// ---------------------------------------------------------------------------
// 3. Edge pass 1: one wave per dst; half=l>>5 edge slot, h=l&31 head+16B slot.
//    Batch 16 edges (8/half); bf16 alpha; f32x2 pk-fma. b1 folded into h1b.
__global__ __launch_bounds__(256) void k_edge1(
        const int* __restrict__ rs, const int* __restrict__ csr,
        const u16* __restrict__ h1b, const u16* __restrict__ asrcb,
        const u16* __restrict__ adstb, u16* __restrict__ outb) {
    int d = blockIdx.x * 4 + (threadIdx.x >> 6);
    if (d >= N) return;
    int l = threadIdx.x & 63;
    int half = l >> 5, h = l & 31;
    int beg = rs[d], end = rs[d + 1];
    float adh = bf2f(adstb[(size_t)d * H1 + h]);
    float wself = __expf(leaky(bf2f(asrcb[(size_t)d * H1 + h]) + adh));
    float w0 = half ? 0.f : wself;
    float den = w0;
    f32x2 c0, c1, c2, c3;
    {
        uint4 vd = *(const uint4*)(h1b + (size_t)d * 256 + 8 * (h ^ (d & 7)));
        c0 = up2v(vd.x) * w0;
        c1 = up2v(vd.y) * w0;
        c2 = up2v(vd.z) * w0;
        c3 = up2v(vd.w) * w0;
    }
    const uint4 z4 = {0u, 0u, 0u, 0u};
    for (int i0 = beg; i0 < end; i0 += 16) {
        int s[8]; u16 avu[8]; uint4 v[8];
#pragma unroll
        for (int k = 0; k < 8; k++) {
            int i = i0 + 2 * k + half;
            s[k] = (i < end) ? csr[i] : -1;
        }
#pragma unroll
        for (int k = 0; k < 8; k++) {
            avu[k] = 0; v[k] = z4;
            if (s[k] >= 0) {
                avu[k] = asrcb[(size_t)s[k] * H1 + h];
                v[k] = *(const uint4*)(h1b + (size_t)s[k] * 256 + 8 * (h ^ (s[k] & 7)));
            }
        }
#pragma unroll
        for (int k = 0; k < 8; k++) {
            float wv = (s[k] >= 0) ? __expf(leaky(bf2f(avu[k]) + adh)) : 0.f;
            den += wv;
            f32x2 w2v = {wv, wv};
            c0 = __builtin_elementwise_fma(up2v(v[k].x), w2v, c0);
            c1 = __builtin_elementwise_fma(up2v(v[k].y), w2v, c1);
            c2 = __builtin_elementwise_fma(up2v(v[k].z), w2v, c2);
            c3 = __builtin_elementwise_fma(up2v(v[k].w), w2v, c3);
        }
    }
    den += __shfl_xor(den, 32, 64);
    c0.x += __shfl_xor(c0.x, 32, 64); c0.y += __shfl_xor(c0.y, 32, 64);
    c1.x += __shfl_xor(c1.x, 32, 64); c1.y += __shfl_xor(c1.y, 32, 64);
    c2.x += __shfl_xor(c2.x, 32, 64); c2.y += __shfl_xor(c2.y, 32, 64);
    c3.x += __shfl_xor(c3.x, 32, 64); c3.y += __shfl_xor(c3.y, 32, 64);
    if (!half) {
        float inv = 1.f / (den + 1e-16f);
        uint4 st;
        st.x = pack2(c0.x * inv, c0.y * inv);
        st.y = pack2(c1.x * inv, c1.y * inv);
        st.z = pack2(c2.x * inv, c2.y * inv);
        st.w = pack2(c3.x * inv, c3.y * inv);
        *(uint4*)(outb + (size_t)d * 256 + 8 * (h ^ (d & 7))) = st;
    }
}

// ---------------------------------------------------------------------------
// 4. GEMM2 (MFMA): h2 = h1a @ W2 + b2 (folded) + alpha2 cols (va2t).
//    Staging via global_load_lds width=16 (linear LDS, pre-swizzled global).
__global__ __launch_bounds__(256) void k_gemm2(
        const u16* __restrict__ ab, const u16* __restrict__ w2t,
        const u16* __restrict__ va2t, const float* __restrict__ b2,
        u16* __restrict__ h2b, float* __restrict__ asrc2, float* __restrict__ adst2) {
    __shared__ u16 As[64 * 256];
    int r0 = blockIdx.x * 64;
    int t = threadIdx.x, w = t >> 6, l = t & 63;
    {
        const u16* gsrc = ab + (size_t)r0 * 256;
        int wbase = t & ~63;   // w*64
#pragma unroll
        for (int i = 0; i < 8; i++) {
            __builtin_amdgcn_global_load_lds(
                (const __attribute__((address_space(1))) void*)(gsrc + (size_t)(i * 256 + t) * 8),
                (__attribute__((address_space(3))) void*)(As + (i * 256 + wbase) * 8),
                16, 0, 0);
        }
    }
    __syncthreads();
    f32x4 z = {0.f, 0.f, 0.f, 0.f};
    f32x4 acc[4], acc5 = z;
#pragma unroll
    for (int n = 0; n < 4; n++) acc[n] = z;
    int row = w * 16 + (l & 15);
    int swzA = (row & 7) << 3;
    int j5 = l & 15;                          // va2t row; 0=src,1=dst
    int swz5 = (j5 & 7) << 3;
#pragma unroll
    for (int ks = 0; ks < 8; ks++) {
        int ka = ks * 32 + (l >> 4) * 8;
        bf16x8 a = *(const bf16x8*)(As + row * 256 + (ka ^ swzA));
#pragma unroll
        for (int n = 0; n < 4; n++) {
            int col = n * 16 + (l & 15);
            bf16x8 b = *(const bf16x8*)(w2t + col * 256 + (ka ^ ((col & 7) << 3)));
            acc[n] = __builtin_amdgcn_mfma_f32_16x16x32_bf16(a, b, acc[n], 0, 0, 0);
        }
        bf16x8 b5 = *(const bf16x8*)(va2t + j5 * 256 + (ka ^ swz5));
        acc5 = __builtin_amdgcn_mfma_f32_16x16x32_bf16(a, b5, acc5, 0, 0, 0);
    }
#pragma unroll
    for (int n = 0; n < 4; n++) {
        int col = n * 16 + (l & 15);
        float b2v = b2[col];
#pragma unroll
        for (int r = 0; r < 4; r++) {
            int rr = r0 + w * 16 + (l >> 4) * 4 + r;
            if (rr < N) h2b[(size_t)rr * F2 + col] = f2bf(acc[n][r] + b2v);
        }
    }
#pragma unroll
    for (int r = 0; r < 4; r++) {
        int rr = r0 + w * 16 + (l >> 4) * 4 + r;
        if (rr < N) {
            if (j5 == 0) asrc2[rr] = acc5[r];
            else if (j5 == 1) adst2[rr] = acc5[r];
        }
    }
}

// ---------------------------------------------------------------------------
// 5. Edge pass 2: one wave per node; 8 lanes/edge (q=l>>3); batch 4; f32x2.
__global__ __launch_bounds__(256) void k_edge2(
        const int* __restrict__ rs, const int* __restrict__ csr,
        const u16* __restrict__ h2b, const float* __restrict__ asrc,
        const float* __restrict__ adst, float* __restrict__ out) {
    int d = blockIdx.x * 4 + (threadIdx.x >> 6);
    if (d >= N) return;
    int l = threadIdx.x & 63;
    int q = l >> 3, c8 = (l & 7) * 8;
    int beg = rs[d], end = rs[d + 1];
    float add_ = adst[d];
    float wself = __expf(leaky(asrc[d] + add_));
    float w0 = (q == 0) ? wself : 0.f;
    float den = w0;
    f32x2 c0, c1, c2, c3;
    {
        uint4 vd = *(const uint4*)(h2b + (size_t)d * F2 + c8);
        c0 = up2v(vd.x) * w0;
        c1 = up2v(vd.y) * w0;
        c2 = up2v(vd.z) * w0;
        c3 = up2v(vd.w) * w0;
    }
    const uint4 z4 = {0u, 0u, 0u, 0u};
    for (int i0 = beg; i0 < end; i0 += 32) {
        int s[4]; float av[4]; uint4 v[4];
#pragma unroll
        for (int k = 0; k < 4; k++) {
            int i = i0 + 8 * k + q;
            s[k] = (i < end) ? csr[i] : -1;
        }
#pragma unroll
        for (int k = 0; k < 4; k++) {
            av[k] = 0.f; v[k] = z4;
            if (s[k] >= 0) {
                av[k] = asrc[s[k]];
                v[k] = *(const uint4*)(h2b + (size_t)s[k] * F2 + c8);
            }
        }
#pragma unroll
        for (int k = 0; k < 4; k++) {
            float wv = (s[k] >= 0) ? __expf(leaky(av[k] + add_)) : 0.f;
            den += wv;
            f32x2 w2v = {wv, wv};
            c0 = __builtin_elementwise_fma(up2v(v[k].x), w2v, c0);
            c1 = __builtin_elementwise_fma(up2v(v[k].y), w2v, c1);
            c2 = __builtin_elementwise_fma(up2v(v[k].z), w2v, c2);
            c3 = __builtin_elementwise_fma(up2v(v[k].w), w2v, c3);
        }
    }
#pragma unroll
    for (int o = 8; o < 64; o <<= 1) {
        den += __shfl_xor(den, o, 64);
        c0.x += __shfl_xor(c0.x, o, 64); c0.y += __shfl_xor(c0.y, o, 64);
        c1.x += __shfl_xor(c1.x, o, 64); c1.y += __shfl_xor(c1.y, o, 64);
        c2.x += __shfl_xor(c2.x, o, 64); c2.y += __shfl_xor(c2.y, o, 64);
        c3.x += __shfl_xor(c3.x, o, 64); c3.y += __shfl_xor(c3.y, o, 64);
    }
    if (q == 0) {
        float inv = 1.f / (den + 1e-16f);
        float4 o1, o2;
        o1.x = 1.f / (1.f + __expf(-(c0.x * inv)));
        o1.y = 1.f / (1.f + __expf(-(c0.y * inv)));
        o1.z = 1.f / (1.f + __expf(-(c1.x * inv)));
        o1.w = 1.f / (1.f + __expf(-(c1.y * inv)));
        o2.x = 1.f / (1.f + __expf(-(c2.x * inv)));
        o2.y = 1.f / (1.f + __expf(-(c2.y * inv)));
        o2.z = 1.f / (1.f + __expf(-(c3.x * inv)));
        o2.w = 1.f / (1.f + __expf(-(c3.y * inv)));
        *(float4*)(out + (size_t)d * F2 + c8) = o1;
        *(float4*)(out + (size_t)d * F2 + c8 + 4) = o2;
    }
}

// ---------------------------------------------------------------------------
extern "C" void kernel_launch(void* const* d_in, const int* in_sizes, int n_in,
                              void* d_out, int out_size, void* d_ws, size_t ws_size,
                              hipStream_t stream) {
    const float* x   = (const float*)d_in[0];
    const void*  ei  = d_in[1];
    const float* W1  = (const float*)d_in[2];
    const float* as1 = (const float*)d_in[3];
    const float* ad1 = (const float*)d_in[4];
    const float* b1  = (const float*)d_in[5];
    const float* W2  = (const float*)d_in[6];
    const float* a2s = (const float*)d_in[7];
    const float* a2d = (const float*)d_in[8];
    const float* b2  = (const float*)d_in[9];
    float* out = (float*)d_out;

    char* wp = (char*)d_ws;
    size_t off = 0;
    auto alloc = [&](size_t bytes) {
        void* p = wp + off;
        off = (off + bytes + 255) & ~(size_t)255;
        return p;
    };
    int* deg   = (int*)alloc((size_t)N * 4);
    int* rs    = (int*)alloc((size_t)(N + 1) * 4);
    int* rs2   = (int*)alloc((size_t)N * 4);
    int* bsum  = (int*)alloc((size_t)NB * 4);
    int* csr   = (int*)alloc((size_t)E * 4);
    u16* w1t   = (u16*)alloc((size_t)W1SZ * 2);
    u16* w2t   = (u16*)alloc((size_t)W2SZ * 2);
    u16* va1t  = (u16*)alloc((size_t)VA1SZ * 2);
    u16* va2t  = (u16*)alloc((size_t)VA2SZ * 2);
    u16* h1b   = (u16*)alloc((size_t)NPAD * F1 * 2);
    u16* h1ab  = (u16*)alloc((size_t)NPAD * F1 * 2);
    u16* h2b   = (u16*)alloc((size_t)NPAD * F2 * 2);
    u16* asrc1b = (u16*)alloc((size_t)N * H1 * 2);
    u16* adst1b = (u16*)alloc((size_t)N * H1 * 2);
    float* asrc2 = (float*)alloc((size_t)N * 4);
    float* adst2 = (float*)alloc((size_t)N * 4);

    k_init<<<INITB, 256, 0, stream>>>(W1, W2, as1, ad1, a2s, a2d,
                                      w1t, w2t, va1t, va2t, deg);
    k_gemm1count<<<GB1 + CB, 256, 0, stream>>>(x, w1t, va1t, b1, h1b,
                                               asrc1b, adst1b, ei, deg);
    {
        void* cargs[] = {(void*)&ei, (void*)&deg, (void*)&bsum,
                         (void*)&rs, (void*)&rs2, (void*)&csr};
        hipLaunchCooperativeKernel((void*)k_csr, dim3(CSRB), dim3(256),
                                   cargs, 0, stream);
    }
    k_edge1<<<(N + 3) / 4, 256, 0, stream>>>(rs, csr, h1b, asrc1b, adst1b, h1ab);
    k_gemm2<<<GB1, 256, 0, stream>>>(h1ab, w2t, va2t, b2, h2b, asrc2, adst2);
    k_edge2<<<(N + 3) / 4, 256, 0, stream>>>(rs, csr, h2b, asrc2, adst2, out);
}

// Round 13
// 230.225 us; speedup vs baseline: 1.7456x; 1.7456x over previous
//
#include <hip/hip_runtime.h>
#include <hip/hip_bf16.h>

constexpr int N  = 50000;
constexpr int E  = 800000;
constexpr int F0 = 128;
constexpr int H1 = 32;
constexpr int F1 = 256;
constexpr int F2 = 64;
constexpr int NB = (N + 255) / 256;        // 196 scan blocks
constexpr int NPAD = 782 * 64;             // 50048
constexpr int W1SZ = F0 * F1;              // 32768
constexpr int W2SZ = F1 * F2;              // 16384
constexpr int VA1SZ = 64 * F0;             // 8192
constexpr int VA2SZ = 16 * F1;             // 4096
constexpr int PREPB = (W1SZ + W2SZ + VA1SZ + VA2SZ) / 256;  // 240
constexpr int INITB = PREPB + NB;          // 436
constexpr int GB1 = NPAD / 64;             // 782 gemm1 blocks
constexpr int CB  = (E + 255) / 256;       // 3125 edge-grid blocks
constexpr float NEG_SLOPE = 0.2f;

typedef unsigned short u16;
typedef unsigned int   u32;
typedef __attribute__((ext_vector_type(8))) short bf16x8;
typedef __attribute__((ext_vector_type(4))) float f32x4;
typedef __attribute__((ext_vector_type(2))) float f32x2;

__device__ __forceinline__ float leaky(float e) {
    return fmaxf(e, 0.f) + NEG_SLOPE * fminf(e, 0.f);
}
__device__ __forceinline__ float bf2f(u16 u) {
    u32 v = ((u32)u) << 16;
    return __builtin_bit_cast(float, v);
}
__device__ __forceinline__ u16 f2bf(float f) {
    u32 u = __builtin_bit_cast(u32, f);
    u += 0x7fffu + ((u >> 16) & 1u);
    return (u16)(u >> 16);
}
__device__ __forceinline__ u32 pack2(float a, float b) {
    return (u32)f2bf(a) | ((u32)f2bf(b) << 16);
}
__device__ __forceinline__ f32x2 up2v(u32 v) {
    f32x2 r;
    r.x = __builtin_bit_cast(float, v << 16);
    r.y = __builtin_bit_cast(float, v & 0xffff0000u);
    return r;
}

// in-wave edge_index dtype check: int64 data -> first 64 u64 all < N
__device__ __forceinline__ int is64_check(const void* ei) {
    const unsigned long long* p = (const unsigned long long*)ei;
    unsigned long long v = p[threadIdx.x & 63];
    return __all(v < (unsigned long long)N) ? 1 : 0;
}
__device__ __forceinline__ int load_idx(const void* ei, long long i, int is64) {
    return is64 ? (int)((const long long*)ei)[i] : ((const int*)ei)[i];
}

// ---------------------------------------------------------------------------
// 0. init: prep weights (fp32->bf16, [n][k] transposed, pre-swizzled) +
//    folded attention cols, AND zero deg. One dispatch.
__global__ __launch_bounds__(256) void k_init(
        const float* __restrict__ W1, const float* __restrict__ W2,
        const float* __restrict__ as1, const float* __restrict__ ad1,
        const float* __restrict__ a2s, const float* __restrict__ a2d,
        u16* __restrict__ w1t, u16* __restrict__ w2t,
        u16* __restrict__ va1t, u16* __restrict__ va2t, int* __restrict__ deg) {
    int b = blockIdx.x;
    if (b >= PREPB) {
        int i = (b - PREPB) * 256 + threadIdx.x;
        if (i < N) deg[i] = 0;
        return;
    }
    int i = b * 256 + threadIdx.x;
    if (i < W1SZ) {
        int n = i >> 7, k = i & 127;
        w1t[(n << 7) + (k ^ ((n & 7) << 3))] = f2bf(W1[k * F1 + n]);
    } else if (i < W1SZ + W2SZ) {
        int j = i - W1SZ;
        int n = j >> 8, k = j & 255;
        w2t[(n << 8) + (k ^ ((n & 7) << 3))] = f2bf(W2[k * F2 + n]);
    } else if (i < W1SZ + W2SZ + VA1SZ) {
        int j = i - W1SZ - W2SZ;
        int c = j >> 7, k = j & 127;          // c: 0-31 src, 32-63 dst
        const float* a = (c < 32) ? as1 : ad1;
        int h = c & 31;
        float s = 0.f;
#pragma unroll
        for (int cc = 0; cc < 8; cc++) s += W1[k * F1 + h * 8 + cc] * a[h * 8 + cc];
        va1t[(c << 7) + (k ^ ((c & 7) << 3))] = f2bf(s);
    } else if (i < W1SZ + W2SZ + VA1SZ + VA2SZ) {
        int j = i - W1SZ - W2SZ - VA1SZ;
        int jj = j >> 8, k = j & 255;
        float s = 0.f;
        if (jj < 2) {
            const float* a = jj ? a2d : a2s;
            for (int c = 0; c < 64; c++) s += W2[k * F2 + c] * a[c];
        }
        va2t[(jj << 8) + (k ^ ((jj & 7) << 3))] = f2bf(s);
    }
}

// ---------------------------------------------------------------------------
// 1. Fused GEMM1 (MFMA, blocks < GB1) + edge COUNT (blocks >= GB1).
__global__ __launch_bounds__(256) void k_gemm1count(
        const float* __restrict__ x, const u16* __restrict__ w1t,
        const u16* __restrict__ va1t, const float* __restrict__ b1,
        u16* __restrict__ h1b, u16* __restrict__ asrc1b, u16* __restrict__ adst1b,
        const void* __restrict__ ei, int* __restrict__ deg) {
    if (blockIdx.x >= GB1) {
        int is64 = is64_check(ei);
        int e = (blockIdx.x - GB1) * 256 + threadIdx.x;
        if (e < E) {
            int dst = load_idx(ei, (long long)E + e, is64);
            atomicAdd(&deg[dst], 1);
        }
        return;
    }
    __shared__ u16 As[64 * 128];   // 16KB, swizzled rows
    int r0 = blockIdx.x * 64;
    int t = threadIdx.x, w = t >> 6, l = t & 63;
    {   // stage: thread t -> row t>>2, 32 cols at (t&3)*32; fp32->bf16 inline
        int r = t >> 2, k0 = (t & 3) * 32, rr = r0 + r;
        int swz = (r & 7) << 3;
        float4 f[8];
        if (rr < N) {
            const float4* px = (const float4*)(x + (size_t)rr * F0 + k0);
#pragma unroll
            for (int j = 0; j < 8; j++) f[j] = px[j];
        } else {
#pragma unroll
            for (int j = 0; j < 8; j++) f[j] = make_float4(0.f, 0.f, 0.f, 0.f);
        }
#pragma unroll
        for (int g = 0; g < 4; g++) {
            uint4 st;
            st.x = pack2(f[2 * g].x, f[2 * g].y);
            st.y = pack2(f[2 * g].z, f[2 * g].w);
            st.z = pack2(f[2 * g + 1].x, f[2 * g + 1].y);
            st.w = pack2(f[2 * g + 1].z, f[2 * g + 1].w);
            *(uint4*)(As + r * 128 + ((k0 + 8 * g) ^ swz)) = st;
        }
    }
    bf16x8 bfrag[4][4];
    float b1v[4];
#pragma unroll
    for (int n = 0; n < 4; n++) {
        int col = w * 64 + n * 16 + (l & 15);
        b1v[n] = b1[col];
        const u16* wrow = w1t + col * 128;
        int swz = (col & 7) << 3;
#pragma unroll
        for (int ks = 0; ks < 4; ks++)
            bfrag[n][ks] = *(const bf16x8*)(wrow + ((ks * 32 + (l >> 4) * 8) ^ swz));
    }
    __syncthreads();
    f32x4 z = {0.f, 0.f, 0.f, 0.f};
    f32x4 acc[4][4], acc5[4];
#pragma unroll
    for (int m = 0; m < 4; m++) {
        acc5[m] = z;
#pragma unroll
        for (int n = 0; n < 4; n++) acc[m][n] = z;
    }
    int c5 = w * 16 + (l & 15);               // alpha col 0..63
    const u16* varow = va1t + c5 * 128;
    int swz5 = (c5 & 7) << 3;
#pragma unroll
    for (int ks = 0; ks < 4; ks++) {
        bf16x8 b5 = *(const bf16x8*)(varow + ((ks * 32 + (l >> 4) * 8) ^ swz5));
#pragma unroll
        for (int m = 0; m < 4; m++) {
            int row = m * 16 + (l & 15);
            bf16x8 a = *(const bf16x8*)(As + row * 128 +
                                        ((ks * 32 + (l >> 4) * 8) ^ ((row & 7) << 3)));
#pragma unroll
            for (int n = 0; n < 4; n++)
                acc[m][n] = __builtin_amdgcn_mfma_f32_16x16x32_bf16(a, bfrag[n][ks], acc[m][n], 0, 0, 0);
            acc5[m] = __builtin_amdgcn_mfma_f32_16x16x32_bf16(a, b5, acc5[m], 0, 0, 0);
        }
    }
#pragma unroll
    for (int m = 0; m < 4; m++) {
        int rbase = r0 + m * 16 + (l >> 4) * 4;
#pragma unroll
        for (int n = 0; n < 4; n++) {
            int col = w * 64 + n * 16 + (l & 15);
#pragma unroll
            for (int r = 0; r < 4; r++) {
                int rr = rbase + r;
                if (rr < N)
                    h1b[(size_t)rr * 256 + (col ^ ((rr & 7) << 3))] = f2bf(acc[m][n][r] + b1v[n]);
            }
        }
#pragma unroll
        for (int r = 0; r < 4; r++) {
            int rr = rbase + r;
            if (rr < N) {
                u16 v = f2bf(acc5[m][r]);
                if (c5 < 32) asrc1b[(size_t)rr * H1 + c5] = v;
                else         adst1b[(size_t)rr * H1 + (c5 - 32)] = v;
            }
        }
    }
}

// ---------------------------------------------------------------------------
// 2a. per-block sums of deg.
__global__ __launch_bounds__(256) void k_bsum(const int* __restrict__ deg, int* __restrict__ bsum) {
    int b = blockIdx.x, t = threadIdx.x, i = b * 256 + t;
    int v = (i < N) ? deg[i] : 0;
#pragma unroll
    for (int o = 1; o < 64; o <<= 1) v += __shfl_xor(v, o, 64);
    __shared__ int sw[4];
    if ((t & 63) == 0) sw[t >> 6] = v;
    __syncthreads();
    if (t == 0) bsum[b] = sw[0] + sw[1] + sw[2] + sw[3];
}

// 2b. fused bscan + rs.
__global__ __launch_bounds__(256) void k_rs2(
        const int* __restrict__ deg, const int* __restrict__ bsum,
        int* __restrict__ rs, int* __restrict__ rs2) {
    __shared__ int sb[NB];
    __shared__ int wtot[4];
    __shared__ int wtot2[4];
    int b = blockIdx.x, t = threadIdx.x, lane = t & 63, wy = t >> 6;
    int v = (t < NB) ? bsum[t] : 0;
    int inc = v;
#pragma unroll
    for (int o = 1; o < 64; o <<= 1) { int u = __shfl_up(inc, o, 64); if (lane >= o) inc += u; }
    if (lane == 63) wtot[wy] = inc;
    __syncthreads();
    int offs = 0;
    for (int k = 0; k < wy; k++) offs += wtot[k];
    if (t < NB) sb[t] = offs + inc - v;
    if (b == 0 && t == NB - 1) rs[N] = offs + inc;
    __syncthreads();
    int base = sb[b];
    int i = b * 256 + t;
    int dv = (i < N) ? deg[i] : 0;
    int dinc = dv;
#pragma unroll
    for (int o = 1; o < 64; o <<= 1) { int u = __shfl_up(dinc, o, 64); if (lane >= o) dinc += u; }
    if (lane == 63) wtot2[wy] = dinc;
    __syncthreads();
    int o2 = base;
    for (int k = 0; k < wy; k++) o2 += wtot2[k];
    if (i < N) {
        int e = o2 + dinc - dv;
        rs[i] = e;
        rs2[i] = e;
    }
}

// 2c. scatter — STANDALONE (low VGPR, high occupancy).
__global__ void k_scatter(const void* __restrict__ ei,
                          int* __restrict__ rs2, int* __restrict__ csr) {
    int is64 = is64_check(ei);
    int e = blockIdx.x * blockDim.x + threadIdx.x;
    if (e >= E) return;
    int src = load_idx(ei, e, is64);
    int dst = load_idx(ei, (long long)E + e, is64);
    int pos = atomicAdd(&rs2[dst], 1);
    csr[pos] = src;
}

// ---------------------------------------------------------------------------
// 3. Edge pass 1: one wave per dst; half=l>>5 edge slot, h=l&31 head+16B slot.
//    Batch 16 edges (8/half); bf16 alpha; f32x2 pk-fma. b1 folded into h1b.
__global__ __launch_bounds__(256) void k_edge1(
        const int* __restrict__ rs, const int* __restrict__ csr,
        const u16* __restrict__ h1b, const u16* __restrict__ asrcb,
        const u16* __restrict__ adstb, u16* __restrict__ outb) {
    int d = blockIdx.x * 4 + (threadIdx.x >> 6);
    if (d >= N) return;
    int l = threadIdx.x & 63;
    int half = l >> 5, h = l & 31;
    int beg = rs[d], end = rs[d + 1];
    float adh = bf2f(adstb[(size_t)d * H1 + h]);
    float wself = __expf(leaky(bf2f(asrcb[(size_t)d * H1 + h]) + adh));
    float w0 = half ? 0.f : wself;
    float den = w0;
    f32x2 c0, c1, c2, c3;
    {
        uint4 vd = *(const uint4*)(h1b + (size_t)d * 256 + 8 * (h ^ (d & 7)));
        c0 = up2v(vd.x) * w0;
        c1 = up2v(vd.y) * w0;
        c2 = up2v(vd.z) * w0;
        c3 = up2v(vd.w) * w0;
    }
    const uint4 z4 = {0u, 0u, 0u, 0u};
    for (int i0 = beg; i0 < end; i0 += 16) {
        int s[8]; u16 avu[8]; uint4 v[8];
#pragma unroll
        for (int k = 0; k < 8; k++) {
            int i = i0 + 2 * k + half;
            s[k] = (i < end) ? csr[i] : -1;
        }
#pragma unroll
        for (int k = 0; k < 8; k++) {
            avu[k] = 0; v[k] = z4;
            if (s[k] >= 0) {
                avu[k] = asrcb[(size_t)s[k] * H1 + h];
                v[k] = *(const uint4*)(h1b + (size_t)s[k] * 256 + 8 * (h ^ (s[k] & 7)));
            }
        }
#pragma unroll
        for (int k = 0; k < 8; k++) {
            float wv = (s[k] >= 0) ? __expf(leaky(bf2f(avu[k]) + adh)) : 0.f;
            den += wv;
            f32x2 w2v = {wv, wv};
            c0 = __builtin_elementwise_fma(up2v(v[k].x), w2v, c0);
            c1 = __builtin_elementwise_fma(up2v(v[k].y), w2v, c1);
            c2 = __builtin_elementwise_fma(up2v(v[k].z), w2v, c2);
            c3 = __builtin_elementwise_fma(up2v(v[k].w), w2v, c3);
        }
    }
    den += __shfl_xor(den, 32, 64);
    c0.x += __shfl_xor(c0.x, 32, 64); c0.y += __shfl_xor(c0.y, 32, 64);
    c1.x += __shfl_xor(c1.x, 32, 64); c1.y += __shfl_xor(c1.y, 32, 64);
    c2.x += __shfl_xor(c2.x, 32, 64); c2.y += __shfl_xor(c2.y, 32, 64);
    c3.x += __shfl_xor(c3.x, 32, 64); c3.y += __shfl_xor(c3.y, 32, 64);
    if (!half) {
        float inv = 1.f / (den + 1e-16f);
        uint4 st;
        st.x = pack2(c0.x * inv, c0.y * inv);
        st.y = pack2(c1.x * inv, c1.y * inv);
        st.z = pack2(c2.x * inv, c2.y * inv);
        st.w = pack2(c3.x * inv, c3.y * inv);
        *(uint4*)(outb + (size_t)d * 256 + 8 * (h ^ (d & 7))) = st;
    }
}

// ---------------------------------------------------------------------------
// 4. GEMM2 (MFMA): h2 = h1a @ W2 + b2 (folded) + alpha2 cols (va2t).
//    Staging via global_load_lds width=16 (linear LDS, pre-swizzled global).
__global__ __launch_bounds__(256) void k_gemm2(
        const u16* __restrict__ ab, const u16* __restrict__ w2t,
        const u16* __restrict__ va2t, const float* __restrict__ b2,
        u16* __restrict__ h2b, float* __restrict__ asrc2, float* __restrict__ adst2) {
    __shared__ u16 As[64 * 256];
    int r0 = blockIdx.x * 64;
    int t = threadIdx.x, w = t >> 6, l = t & 63;
    {
        const u16* gsrc = ab + (size_t)r0 * 256;
        int wbase = t & ~63;   // w*64
#pragma unroll
        for (int i = 0; i < 8; i++) {
            __builtin_amdgcn_global_load_lds(
                (const __attribute__((address_space(1))) void*)(gsrc + (size_t)(i * 256 + t) * 8),
                (__attribute__((address_space(3))) void*)(As + (i * 256 + wbase) * 8),
                16, 0, 0);
        }
    }
    __syncthreads();
    f32x4 z = {0.f, 0.f, 0.f, 0.f};
    f32x4 acc[4], acc5 = z;
#pragma unroll
    for (int n = 0; n < 4; n++) acc[n] = z;
    int row = w * 16 + (l & 15);
    int swzA = (row & 7) << 3;
    int j5 = l & 15;                          // va2t row; 0=src,1=dst
    int swz5 = (j5 & 7) << 3;
#pragma unroll
    for (int ks = 0; ks < 8; ks++) {
        int ka = ks * 32 + (l >> 4) * 8;
        bf16x8 a = *(const bf16x8*)(As + row * 256 + (ka ^ swzA));
#pragma unroll
        for (int n = 0; n < 4; n++) {
            int col = n * 16 + (l & 15);
            bf16x8 b = *(const bf16x8*)(w2t + col * 256 + (ka ^ ((col & 7) << 3)));
            acc[n] = __builtin_amdgcn_mfma_f32_16x16x32_bf16(a, b, acc[n], 0, 0, 0);
        }
        bf16x8 b5 = *(const bf16x8*)(va2t + j5 * 256 + (ka ^ swz5));
        acc5 = __builtin_amdgcn_mfma_f32_16x16x32_bf16(a, b5, acc5, 0, 0, 0);
    }
#pragma unroll
    for (int n = 0; n < 4; n++) {
        int col = n * 16 + (l & 15);
        float b2v = b2[col];
#pragma unroll
        for (int r = 0; r < 4; r++) {
            int rr = r0 + w * 16 + (l >> 4) * 4 + r;
            if (rr < N) h2b[(size_t)rr * F2 + col] = f2bf(acc[n][r] + b2v);
        }
    }
#pragma unroll
    for (int r = 0; r < 4; r++) {
        int rr = r0 + w * 16 + (l >> 4) * 4 + r;
        if (rr < N) {
            if (j5 == 0) asrc2[rr] = acc5[r];
            else if (j5 == 1) adst2[rr] = acc5[r];
        }
    }
}

// ---------------------------------------------------------------------------
// 5. Edge pass 2: one wave per node; 8 lanes/edge (q=l>>3); batch 4; f32x2.
//    b2 folded into h2b.
__global__ __launch_bounds__(256) void k_edge2(
        const int* __restrict__ rs, const int* __restrict__ csr,
        const u16* __restrict__ h2b, const float* __restrict__ asrc,
        const float* __restrict__ adst, float* __restrict__ out) {
    int d = blockIdx.x * 4 + (threadIdx.x >> 6);
    if (d >= N) return;
    int l = threadIdx.x & 63;
    int q = l >> 3, c8 = (l & 7) * 8;
    int beg = rs[d], end = rs[d + 1];
    float add_ = adst[d];
    float wself = __expf(leaky(asrc[d] + add_));
    float w0 = (q == 0) ? wself : 0.f;
    float den = w0;
    f32x2 c0, c1, c2, c3;
    {
        uint4 vd = *(const uint4*)(h2b + (size_t)d * F2 + c8);
        c0 = up2v(vd.x) * w0;
        c1 = up2v(vd.y) * w0;
        c2 = up2v(vd.z) * w0;
        c3 = up2v(vd.w) * w0;
    }
    const uint4 z4 = {0u, 0u, 0u, 0u};
    for (int i0 = beg; i0 < end; i0 += 32) {
        int s[4]; float av[4]; uint4 v[4];
#pragma unroll
        for (int k = 0; k < 4; k++) {
            int i = i0 + 8 * k + q;
            s[k] = (i < end) ? csr[i] : -1;
        }
#pragma unroll
        for (int k = 0; k < 4; k++) {
            av[k] = 0.f; v[k] = z4;
            if (s[k] >= 0) {
                av[k] = asrc[s[k]];
                v[k] = *(const uint4*)(h2b + (size_t)s[k] * F2 + c8);
            }
        }
#pragma unroll
        for (int k = 0; k < 4; k++) {
            float wv = (s[k] >= 0) ? __expf(leaky(av[k] + add_)) : 0.f;
            den += wv;
            f32x2 w2v = {wv, wv};
            c0 = __builtin_elementwise_fma(up2v(v[k].x), w2v, c0);
            c1 = __builtin_elementwise_fma(up2v(v[k].y), w2v, c1);
            c2 = __builtin_elementwise_fma(up2v(v[k].z), w2v, c2);
            c3 = __builtin_elementwise_fma(up2v(v[k].w), w2v, c3);
        }
    }
#pragma unroll
    for (int o = 8; o < 64; o <<= 1) {
        den += __shfl_xor(den, o, 64);
        c0.x += __shfl_xor(c0.x, o, 64); c0.y += __shfl_xor(c0.y, o, 64);
        c1.x += __shfl_xor(c1.x, o, 64); c1.y += __shfl_xor(c1.y, o, 64);
        c2.x += __shfl_xor(c2.x, o, 64); c2.y += __shfl_xor(c2.y, o, 64);
        c3.x += __shfl_xor(c3.x, o, 64); c3.y += __shfl_xor(c3.y, o, 64);
    }
    if (q == 0) {
        float inv = 1.f / (den + 1e-16f);
        float4 o1, o2;
        o1.x = 1.f / (1.f + __expf(-(c0.x * inv)));
        o1.y = 1.f / (1.f + __expf(-(c0.y * inv)));
        o1.z = 1.f / (1.f + __expf(-(c1.x * inv)));
        o1.w = 1.f / (1.f + __expf(-(c1.y * inv)));
        o2.x = 1.f / (1.f + __expf(-(c2.x * inv)));
        o2.y = 1.f / (1.f + __expf(-(c2.y * inv)));
        o2.z = 1.f / (1.f + __expf(-(c3.x * inv)));
        o2.w = 1.f / (1.f + __expf(-(c3.y * inv)));
        *(float4*)(out + (size_t)d * F2 + c8) = o1;
        *(float4*)(out + (size_t)d * F2 + c8 + 4) = o2;
    }
}

// ---------------------------------------------------------------------------
extern "C" void kernel_launch(void* const* d_in, const int* in_sizes, int n_in,
                              void* d_out, int out_size, void* d_ws, size_t ws_size,
                              hipStream_t stream) {
    const float* x   = (const float*)d_in[0];
    const void*  ei  = d_in[1];
    const float* W1  = (const float*)d_in[2];
    const float* as1 = (const float*)d_in[3];
    const float* ad1 = (const float*)d_in[4];
    const float* b1  = (const float*)d_in[5];
    const float* W2  = (const float*)d_in[6];
    const float* a2s = (const float*)d_in[7];
    const float* a2d = (const float*)d_in[8];
    const float* b2  = (const float*)d_in[9];
    float* out = (float*)d_out;

    char* wp = (char*)d_ws;
    size_t off = 0;
    auto alloc = [&](size_t bytes) {
        void* p = wp + off;
        off = (off + bytes + 255) & ~(size_t)255;
        return p;
    };
    int* deg   = (int*)alloc((size_t)N * 4);
    int* rs    = (int*)alloc((size_t)(N + 1) * 4);
    int* rs2   = (int*)alloc((size_t)N * 4);
    int* bsum  = (int*)alloc((size_t)NB * 4);
    int* csr   = (int*)alloc((size_t)E * 4);
    u16* w1t   = (u16*)alloc((size_t)W1SZ * 2);
    u16* w2t   = (u16*)alloc((size_t)W2SZ * 2);
    u16* va1t  = (u16*)alloc((size_t)VA1SZ * 2);
    u16* va2t  = (u16*)alloc((size_t)VA2SZ * 2);
    u16* h1b   = (u16*)alloc((size_t)NPAD * F1 * 2);
    u16* h1ab  = (u16*)alloc((size_t)NPAD * F1 * 2);
    u16* h2b   = (u16*)alloc((size_t)NPAD * F2 * 2);
    u16* asrc1b = (u16*)alloc((size_t)N * H1 * 2);
    u16* adst1b = (u16*)alloc((size_t)N * H1 * 2);
    float* asrc2 = (float*)alloc((size_t)N * 4);
    float* adst2 = (float*)alloc((size_t)N * 4);

    k_init<<<INITB, 256, 0, stream>>>(W1, W2, as1, ad1, a2s, a2d,
                                      w1t, w2t, va1t, va2t, deg);
    k_gemm1count<<<GB1 + CB, 256, 0, stream>>>(x, w1t, va1t, b1, h1b,
                                               asrc1b, adst1b, ei, deg);
    k_bsum<<<NB, 256, 0, stream>>>(deg, bsum);
    k_rs2<<<NB, 256, 0, stream>>>(deg, bsum, rs, rs2);
    k_scatter<<<CB, 256, 0, stream>>>(ei, rs2, csr);
    k_edge1<<<(N + 3) / 4, 256, 0, stream>>>(rs, csr, h1b, asrc1b, adst1b, h1ab);
    k_gemm2<<<GB1, 256, 0, stream>>>(h1ab, w2t, va2t, b2, h2b, asrc2, adst2);
    k_edge2<<<(N + 3) / 4, 256, 0, stream>>>(rs, csr, h2b, asrc2, adst2, out);
}